// Round 10
// baseline (6906.402 us; speedup 1.0000x reference)
//
#include <hip/hip_runtime.h>
#include <hip/hip_bf16.h>

// IN=128, H=512, N=2048, W=64, OUT=128, R=4, T=128, B=64
// gate K=896 (x 0:128 | read_vec 128:384 | h 384:896), gate rows 2048
// Wkb rows: 0..127 = Wout, 128..447 = Wkey (read keys 128..383, write key 384..447)
//
// R10 = R9 concept (LDS-free, barrier-free gates GEMM: lane loads its MFMA A/B
// fragments directly from global into registers) with the R9 bug fixed:
// ALL coherent loads go through __hip_atomic_load (compiler-tracked vmcnt) —
// R9's asm ld_coh16 had no waitcnt, so the in-flight load clobbered reused
// registers -> memory fault. Vector casts replaced with unions.
#define EPSF 1e-8f

typedef __attribute__((ext_vector_type(8))) __bf16 bf8;
typedef __attribute__((ext_vector_type(4))) float f4;
typedef unsigned long long ull;

#define LBAR() do { asm volatile("s_waitcnt lgkmcnt(0)" ::: "memory"); \
                    __builtin_amdgcn_s_barrier(); } while (0)

__device__ __forceinline__ short f2bf(float f) {
  union { __hip_bfloat16 b; short s; } u;
  u.b = __float2bfloat16(f);
  return u.s;
}
__device__ __forceinline__ float sigf(float x) { return 1.f / (1.f + __expf(-x)); }
__device__ __forceinline__ float red16(float v) {
  v += __shfl_xor(v, 1); v += __shfl_xor(v, 2);
  v += __shfl_xor(v, 4); v += __shfl_xor(v, 8);
  return v;
}

// coherent (MALL-visible) helpers
__device__ __forceinline__ void st_coh16(void* p, f4 v) {
  asm volatile("global_store_dwordx4 %0, %1, off sc0 sc1" :: "v"(p), "v"(v) : "memory");
}
__device__ __forceinline__ void st_coh8u(void* p, ull v) {
  asm volatile("global_store_dwordx2 %0, %1, off sc0 sc1" :: "v"(p), "v"(v) : "memory");
}
__device__ __forceinline__ void st_coh4(void* p, float v) {
  asm volatile("global_store_dword %0, %1, off sc0 sc1" :: "v"(p), "v"(v) : "memory");
}
__device__ __forceinline__ void st_coh4u(void* p, unsigned v) {
  asm volatile("global_store_dword %0, %1, off sc0 sc1" :: "v"(p), "v"(v) : "memory");
}
__device__ __forceinline__ void st_coh2(void* p, unsigned v) {
  asm volatile("global_store_short %0, %1, off sc0 sc1" :: "v"(p), "v"(v) : "memory");
}
// compiler-tracked coherent loads (atomic relaxed agent => sc0 sc1 + auto waitcnt)
__device__ __forceinline__ ull ald8(const void* p) {
  return __hip_atomic_load((const ull*)p, __ATOMIC_RELAXED, __HIP_MEMORY_SCOPE_AGENT);
}
__device__ __forceinline__ unsigned ald4(const void* p) {
  return __hip_atomic_load((const unsigned*)p, __ATOMIC_RELAXED, __HIP_MEMORY_SCOPE_AGENT);
}

#define LD8X4(v0,v1,v2,v3,v4,v5,v6,v7,p0,p1,p2,p3,p4,p5,p6,p7) \
  asm volatile( \
    "global_load_dwordx4 %0, %8, off sc0 sc1\n\t" \
    "global_load_dwordx4 %1, %9, off sc0 sc1\n\t" \
    "global_load_dwordx4 %2, %10, off sc0 sc1\n\t" \
    "global_load_dwordx4 %3, %11, off sc0 sc1\n\t" \
    "global_load_dwordx4 %4, %12, off sc0 sc1\n\t" \
    "global_load_dwordx4 %5, %13, off sc0 sc1\n\t" \
    "global_load_dwordx4 %6, %14, off sc0 sc1\n\t" \
    "global_load_dwordx4 %7, %15, off sc0 sc1\n\t" \
    "s_waitcnt vmcnt(0)" \
    : "=&v"(v0),"=&v"(v1),"=&v"(v2),"=&v"(v3),"=&v"(v4),"=&v"(v5),"=&v"(v6),"=&v"(v7) \
    : "v"(p0),"v"(p1),"v"(p2),"v"(p3),"v"(p4),"v"(p5),"v"(p6),"v"(p7) : "memory")

// Grid barrier (R6-R8 proven design): own-flag arrival, checker block 255,
// 8 release lines, relaxed loads, no fences.
__device__ __forceinline__ void gsync(unsigned* bar, unsigned k) {
  asm volatile("s_waitcnt vmcnt(0)" ::: "memory");
  __syncthreads();
  if (threadIdx.x == 0)
    __hip_atomic_store(&bar[blockIdx.x * 16], k, __ATOMIC_RELAXED,
                       __HIP_MEMORY_SCOPE_AGENT);
  if (blockIdx.x == 255) {
    if (threadIdx.x < 64) {
      const int l = threadIdx.x;
      for (;;) {
        unsigned mn = 0xffffffffu;
#pragma unroll
        for (int j = 0; j < 4; ++j) {
          unsigned v = __hip_atomic_load(&bar[(l * 4 + j) * 16], __ATOMIC_RELAXED,
                                         __HIP_MEMORY_SCOPE_AGENT);
          mn = v < mn ? v : mn;
        }
        if (__all(mn >= k)) break;
        __builtin_amdgcn_s_sleep(1);
      }
      if (l < 8)
        __hip_atomic_store(&bar[4096 + l * 16], k, __ATOMIC_RELAXED,
                           __HIP_MEMORY_SCOPE_AGENT);
    }
  } else if (threadIdx.x == 0) {
    const unsigned g = blockIdx.x >> 5;
    while (__hip_atomic_load(&bar[4096 + g * 16], __ATOMIC_RELAXED,
                             __HIP_MEMORY_SCOPE_AGENT) < k)
      __builtin_amdgcn_s_sleep(1);
  }
  __syncthreads();
}

__global__ __launch_bounds__(512, 2) void mann_mega(
    const float* __restrict__ x_seq, const float* __restrict__ Wih,
    const float* __restrict__ Whh, const float* __restrict__ bih,
    const float* __restrict__ bhh, const float* __restrict__ Wout,
    const float* __restrict__ boutp, const float* __restrict__ Wkey,
    const float* __restrict__ bkeyp, const float* __restrict__ alphap,
    const float* __restrict__ gammap, float* __restrict__ out, char* ws) {
  float* rwb0 = (float*)(ws + 33554432);       // 2097152  exps [b][n][r], coherent
  float* rwb1 = (float*)(ws + 35651584);       // 2097152
  float* usage = (float*)(ws + 37748736);      // 524288   private (finalize)
  float* cst = (float*)(ws + 38273024);        // 131072   private (gates)
  short* hb0 = (short*)(ws + 38404096);        // 65536    coherent
  short* hb1 = (short*)(ws + 38469632);        // 65536
  float* rv0 = (float*)(ws + 38535168);        // 65536    atomic-reduced rv
  float* rv1 = (float*)(ws + 38600704);        // 65536
  float* dp = (float*)(ws + 38666240);         // 4096     denom partials
  float* sd0 = (float*)(ws + 38670336);        // 1024     denoms [b][r]
  float* sd1 = (float*)(ws + 38671360);        // 1024
  unsigned* lu = (unsigned*)(ws + 38672384);   // 1024
  unsigned* bar = (unsigned*)(ws + 38673408);  // 20480 (host memset 0)
  short* Wc = (short*)(ws + 38693888);         // 3670016
  short* Wkb = (short*)(ws + 42363904);        // 458752 -> end 42822656

  // M slice for this block: [nl 0..511][w 0..63] fp32, resident all 128 steps
  __shared__ float Mlds[512 * 64];             // 131072 B
  __shared__ union {
    struct { float gbuf[64 * 33]; } g;         // gates accum staging (8448 B)
    struct { float sv[512]; int si[512]; } m;  // finalize argmin
    struct { short hs[512]; float kbuf[256]; float wkbuf[64];
             float rvacc[256]; float wsum[32]; float wps[512]; } a;  // PA
  } sm;
  __shared__ float denl[256];

  const int tid = threadIdx.x;
  const int lane = tid & 63;
  const int wv = tid >> 6;
  const int s = lane & 15;
  const int q = lane >> 4;
  unsigned rnd = 0;

  // ---------------- prologue: weight conversion + lu init ----------------
  {
    const unsigned gid = blockIdx.x * 512 + tid;
    const unsigned gs = 256 * 512;
    for (unsigned i4 = gid; i4 < 458752u; i4 += gs) {  // Wc: 2048x896 shorts
      unsigned e = i4 * 4;
      unsigned row = e / 896u, k = e - row * 896u;
      float4 v = (k < 384u) ? *(const float4*)&Wih[row * 384u + k]
                            : *(const float4*)&Whh[row * 512u + (k - 384u)];
      union { short4 s4; ull u; } o;
      o.s4.x = f2bf(v.x); o.s4.y = f2bf(v.y); o.s4.z = f2bf(v.z); o.s4.w = f2bf(v.w);
      st_coh8u(Wc + e, o.u);
    }
    for (unsigned i4 = gid; i4 < 57344u; i4 += gs) {  // Wkb: 448x512 shorts
      unsigned e = i4 * 4;
      unsigned row = e >> 9, k = e & 511u;
      float4 v = (row < 128u) ? *(const float4*)&Wout[row * 512u + k]
                              : *(const float4*)&Wkey[(row - 128u) * 512u + k];
      union { short4 s4; ull u; } o;
      o.s4.x = f2bf(v.x); o.s4.y = f2bf(v.y); o.s4.z = f2bf(v.z); o.s4.w = f2bf(v.w);
      st_coh8u(Wkb + e, o.u);
    }
    if (gid < 64u) st_coh4u(lu + gid, 0u);  // lu_0 = argmin(zeros) = 0
  }
  gsync(bar, ++rnd);

  for (int t = 0; t < 128; ++t) {
    const int p = t & 1;
    short* hN = p ? hb1 : hb0;
    const short* hP = p ? hb0 : hb1;
    float* rwCur = p ? rwb1 : rwb0;       // exps of step t (coherent in PA)
    const float* rwM1 = p ? rwb0 : rwb1;  // exps of step t-1
    const float* rwM2 = rwCur;            // exps of step t-2 (stale buffer)
    float* sdW = p ? sd1 : sd0;           // denom_{t-1}, written by finalize_t
    const float* sdM2 = p ? sd0 : sd1;    // denom_{t-2}
    float* rvW = p ? rv1 : rv0;           // atomic target of PA_t
    const float* rvR = p ? rv0 : rv1;     // reduced rv of step t-1

    // ========== P1 phase ==========
    if (blockIdx.x < 64) {
      // ---- gates GEMM: LDS-free, barrier-free; direct register fragments ----
      const int j0 = blockIdx.x * 8;
      if (tid < 256) {
        float iv = 1.f;
        if (t > 0) {
          union { ull u; float2 f; } a, b2;
          a.u = ald8(dp + tid * 4); b2.u = ald8(dp + tid * 4 + 2);
          iv = 1.f / (a.f.x + a.f.y + b2.f.x + b2.f.y);
        }
        denl[tid] = iv;  // 1/denom_{t-1}[b*4+r]
      }
      __syncthreads();  // denl ready
      {
        const int msl = wv >> 1, nh = wv & 1;
        const int arow = msl * 16 + s;    // batch row (A m-index = lane&15)
        const int rr = nh * 16 + s;       // weight row within 32-block (B n-index)
        const int gg = rr >> 3, jj = rr & 7;
        const size_t wrow = (size_t)(gg * 512 + j0 + jj) * 896;
        f4 acc = {0.f, 0.f, 0.f, 0.f};
#pragma unroll
        for (int c = 0; c < 28; ++c) {
          const int k0 = c * 32 + q * 8;  // this lane's K offset (A k = q*8..+7)
          union { ull u[2]; short sh[8]; bf8 b8; } au;
          if (c < 4) {
            // x_seq fp32 -> bf16 (normal cached loads, compiler-tracked)
            const float* px = &x_seq[((size_t)t * 64 + arow) * 128 + k0];
            float4 v0 = *(const float4*)px;
            float4 v1 = *(const float4*)(px + 4);
            au.sh[0] = f2bf(v0.x); au.sh[1] = f2bf(v0.y);
            au.sh[2] = f2bf(v0.z); au.sh[3] = f2bf(v0.w);
            au.sh[4] = f2bf(v1.x); au.sh[5] = f2bf(v1.y);
            au.sh[6] = f2bf(v1.z); au.sh[7] = f2bf(v1.w);
          } else if (c < 12) {
            // read_vec = rvR * denl (coherent, compiler-tracked)
            if (t > 0) {
              const int col = k0 - 128;
              const float iv = denl[arow * 4 + (col >> 6)];
              union { ull u; float2 f; } w0, w1, w2, w3;
              w0.u = ald8(rvR + arow * 256 + col);
              w1.u = ald8(rvR + arow * 256 + col + 2);
              w2.u = ald8(rvR + arow * 256 + col + 4);
              w3.u = ald8(rvR + arow * 256 + col + 6);
              au.sh[0] = f2bf(w0.f.x * iv); au.sh[1] = f2bf(w0.f.y * iv);
              au.sh[2] = f2bf(w1.f.x * iv); au.sh[3] = f2bf(w1.f.y * iv);
              au.sh[4] = f2bf(w2.f.x * iv); au.sh[5] = f2bf(w2.f.y * iv);
              au.sh[6] = f2bf(w3.f.x * iv); au.sh[7] = f2bf(w3.f.y * iv);
            } else { au.u[0] = 0; au.u[1] = 0; }
          } else {
            // h_{t-1} bf16 (coherent 2x8B, compiler-tracked)
            if (t > 0) {
              au.u[0] = ald8(hP + arow * 512 + (k0 - 384));
              au.u[1] = ald8(hP + arow * 512 + (k0 - 384) + 4);
            } else { au.u[0] = 0; au.u[1] = 0; }
          }
          bf8 bb = *(const bf8*)&Wc[wrow + k0];  // normal cached (L2-resident)
          acc = __builtin_amdgcn_mfma_f32_16x16x32_bf16(au.b8, bb, acc, 0, 0, 0);
        }
#pragma unroll
        for (int reg = 0; reg < 4; ++reg) {
          int bat = msl * 16 + q * 4 + reg;
          sm.g.gbuf[bat * 33 + rr] = acc[reg];
        }
      }
      LBAR();
      {
        int b = tid >> 3, jj = tid & 7, j = j0 + jj;
        float gi = sm.g.gbuf[b * 33 + jj] + bih[j] + bhh[j];
        float gf = sm.g.gbuf[b * 33 + 8 + jj] + bih[512 + j] + bhh[512 + j];
        float gg2 = sm.g.gbuf[b * 33 + 16 + jj] + bih[1024 + j] + bhh[1024 + j];
        float go = sm.g.gbuf[b * 33 + 24 + jj] + bih[1536 + j] + bhh[1536 + j];
        float co = (t == 0) ? 0.f : cst[b * 512 + j];  // private cached
        float cn = sigf(gf) * co + sigf(gi) * tanhf(gg2);
        float hn = sigf(go) * tanhf(cn);
        cst[b * 512 + j] = cn;
        union { __hip_bfloat16 b16; unsigned short us; } hu;
        hu.b16 = __float2bfloat16(hn);
        st_coh2(hN + b * 512 + j, (unsigned)hu.us);
      }
    } else if (blockIdx.x < 128) {
      // ---- finalize step t-1: denoms -> sdW, usage update, argmin -> lu ----
      if (t > 0) {
        const int b = blockIdx.x - 64;
        f4 dp0, dp1, dp2, dp3, sm2;
        unsigned luv;
        asm volatile(
            "global_load_dwordx4 %0, %6, off sc0 sc1\n\t"
            "global_load_dwordx4 %1, %7, off sc0 sc1\n\t"
            "global_load_dwordx4 %2, %8, off sc0 sc1\n\t"
            "global_load_dwordx4 %3, %9, off sc0 sc1\n\t"
            "global_load_dwordx4 %4, %10, off sc0 sc1\n\t"
            "global_load_dword %5, %11, off sc0 sc1\n\t"
            "s_waitcnt vmcnt(0)"
            : "=&v"(dp0), "=&v"(dp1), "=&v"(dp2), "=&v"(dp3), "=&v"(sm2), "=&v"(luv)
            : "v"((const void*)(dp + (b * 4 + 0) * 4)),
              "v"((const void*)(dp + (b * 4 + 1) * 4)),
              "v"((const void*)(dp + (b * 4 + 2) * 4)),
              "v"((const void*)(dp + (b * 4 + 3) * 4)),
              "v"((const void*)(sdM2 + b * 4)), "v"((const void*)(lu + b))
            : "memory");
        float d0 = dp0.x + dp0.y + dp0.z + dp0.w;
        float d1 = dp1.x + dp1.y + dp1.z + dp1.w;
        float d2 = dp2.x + dp2.y + dp2.z + dp2.w;
        float d3 = dp3.x + dp3.y + dp3.z + dp3.w;
        if (tid == 0) { f4 dv = {d0, d1, d2, d3}; st_coh16(sdW + b * 4, dv); }
        float iC0 = 1.f / d0, iC1 = 1.f / d1, iC2 = 1.f / d2, iC3 = 1.f / d3;
        float iO0 = 0, iO1 = 0, iO2 = 0, iO3 = 0;
        if (t > 1) { iO0 = 1.f / sm2.x; iO1 = 1.f / sm2.y; iO2 = 1.f / sm2.z; iO3 = 1.f / sm2.w; }
        const float sa = sigf(alphap[0]);
        const float ga = gammap[0];
        const int luB = (int)luv;
        f4 ec[4], eo[4];
        {
          const void* pc[4]; const void* po[4];
#pragma unroll
          for (int i = 0; i < 4; ++i) {
            int n = i * 512 + tid;
            pc[i] = (const void*)(rwM1 + ((size_t)b * 2048 + n) * 4);
            po[i] = (const void*)(rwM2 + ((size_t)b * 2048 + n) * 4);
          }
          LD8X4(ec[0], ec[1], ec[2], ec[3], eo[0], eo[1], eo[2], eo[3],
                pc[0], pc[1], pc[2], pc[3], po[0], po[1], po[2], po[3]);
        }
        float vm = INFINITY;
        int im = 0x7fffffff;
#pragma unroll
        for (int i = 0; i < 4; ++i) {
          int n = i * 512 + tid;
          float wps = (t > 1) ? (eo[i].x * iO0 + eo[i].y * iO1 + eo[i].z * iO2 + eo[i].w * iO3)
                              : 0.f;
          float ww = sa * wps + (1.f - sa) * ((n == luB) ? 1.f : 0.f);
          float sn = ec[i].x * iC0 + ec[i].y * iC1 + ec[i].z * iC2 + ec[i].w * iC3;
          float uo = (t == 1) ? 0.f : usage[b * 2048 + n];  // private cached
          float u = ga * uo + sn + ww;
          usage[b * 2048 + n] = u;
          if (u < vm) { vm = u; im = n; }  // n strictly increasing per thread
        }
        sm.m.sv[tid] = vm; sm.m.si[tid] = im;
        LBAR();
        for (int off = 256; off > 0; off >>= 1) {
          if (tid < off) {
            float v2 = sm.m.sv[tid + off]; int j2 = sm.m.si[tid + off];
            if (v2 < sm.m.sv[tid] || (v2 == sm.m.sv[tid] && j2 < sm.m.si[tid])) {
              sm.m.sv[tid] = v2; sm.m.si[tid] = j2;
            }
          }
          LBAR();
        }
        if (tid == 0) st_coh4u(lu + b, (unsigned)sm.m.si[0]);
      }
    } else if (blockIdx.x < 192) {
      // ---- zero rvW for PA_t's atomics ----
      const int bz = blockIdx.x - 128;
      if (tid < 64) { f4 z = {0, 0, 0, 0}; st_coh16(rvW + bz * 256 + tid * 4, z); }
    }
    gsync(bar, ++rnd);

    // ========== PA phase: keys/out + fused M-pass (M in LDS) ==========
    {
      const int b = blockIdx.x >> 2, ch = blockIdx.x & 3;
      if (tid < 128) {
        union { ull u; uint2 v; } hv;
        hv.u = ald8(hN + b * 512 + tid * 4);
        *(uint2*)&sm.a.hs[tid * 4] = hv.v;
      }
      if (tid < 256) sm.a.rvacc[tid] = 0.f;
      unsigned luv = 0;
      if (t > 0) {
        luv = ald4(lu + b);
        // precompute w_prev sums: wps[nl] = sum_r exp_{t-1}[r]/denom_{t-1}[r]
        union { ull u; float2 f; } s0, s1, e0, e1;
        s0.u = ald8(sdW + b * 4); s1.u = ald8(sdW + b * 4 + 2);
        const size_t eb = ((size_t)b * 2048 + ch * 512 + tid) * 4;
        e0.u = ald8(rwM1 + eb); e1.u = ald8(rwM1 + eb + 2);
        sm.a.wps[tid] = e0.f.x / s0.f.x + e0.f.y / s0.f.y +
                        e1.f.x / s1.f.x + e1.f.y / s1.f.y;
      } else {
        sm.a.wps[tid] = 0.f;
      }
      __syncthreads();
      // keys (redundant per block) + out slice: 352 rows = 11 passes x 32
      for (int pp = 0; pp < 11; ++pp) {
        int idx = pp * 32 + wv * 4 + q;
        int wr; float bias;
        if (idx < 320) { wr = 128 + idx; bias = bkeyp[idx]; }
        else { wr = ch * 32 + (idx - 320); bias = boutp[wr]; }
        float acc = 0.f;
#pragma unroll
        for (int i = 0; i < 4; ++i) {
          bf8 w8 = *(const bf8*)&Wkb[(size_t)wr * 512 + i * 128 + s * 8];
          bf8 h8 = *(const bf8*)&sm.a.hs[i * 128 + s * 8];
#pragma unroll
          for (int j = 0; j < 8; ++j) acc += (float)w8[j] * (float)h8[j];
        }
        acc = red16(acc) + bias;
        if (s == 0) {
          if (idx < 256) sm.a.kbuf[idx] = acc;
          else if (idx < 320) sm.a.wkbuf[idx - 256] = acc;
          else out[((size_t)t * 64 + b) * 128 + wr] = acc;  // normal store
        }
      }
      LBAR();
      float4 kn[4];
#pragma unroll
      for (int r = 0; r < 4; ++r) {
        float4 k4 = *(float4*)&sm.a.kbuf[r * 64 + s * 4];
        float ss = k4.x * k4.x + k4.y * k4.y + k4.z * k4.z + k4.w * k4.w;
        ss = red16(ss);
        float iv = 1.f / (sqrtf(ss) + EPSF);
        kn[r].x = k4.x * iv; kn[r].y = k4.y * iv;
        kn[r].z = k4.z * iv; kn[r].w = k4.w * iv;
      }
      const float4 wk = *(float4*)&sm.a.wkbuf[s * 4];
      const float sa = sigf(alphap[0]);
      const int luB = (int)luv;
      float4 rva0 = {0,0,0,0}, rva1 = {0,0,0,0}, rva2 = {0,0,0,0}, rva3 = {0,0,0,0};
      float es0 = 0.f, es1 = 0.f, es2 = 0.f, es3 = 0.f;
      for (int i = 0; i < 16; ++i) {
        const int nl = wv * 64 + i * 4 + q;
        const int n = ch * 512 + nl;
        float4 m4;
        if (t > 0) m4 = *(float4*)&Mlds[nl * 64 + s * 4];
        else { m4.x = 1e-6f; m4.y = 1e-6f; m4.z = 1e-6f; m4.w = 1e-6f; }
        float ssm = m4.x * m4.x + m4.y * m4.y + m4.z * m4.z + m4.w * m4.w;
        float d0 = m4.x * kn[0].x + m4.y * kn[0].y + m4.z * kn[0].z + m4.w * kn[0].w;
        float d1 = m4.x * kn[1].x + m4.y * kn[1].y + m4.z * kn[1].z + m4.w * kn[1].w;
        float d2 = m4.x * kn[2].x + m4.y * kn[2].y + m4.z * kn[2].z + m4.w * kn[2].w;
        float d3 = m4.x * kn[3].x + m4.y * kn[3].y + m4.z * kn[3].z + m4.w * kn[3].w;
        ssm = red16(ssm);
        d0 = red16(d0); d1 = red16(d1); d2 = red16(d2); d3 = red16(d3);
        float iv = 1.f / (sqrtf(ssm) + EPSF);
        float e0 = __expf(d0 * iv), e1 = __expf(d1 * iv);
        float e2 = __expf(d2 * iv), e3 = __expf(d3 * iv);
        rva0.x += e0 * m4.x; rva0.y += e0 * m4.y; rva0.z += e0 * m4.z; rva0.w += e0 * m4.w;
        rva1.x += e1 * m4.x; rva1.y += e1 * m4.y; rva1.z += e1 * m4.z; rva1.w += e1 * m4.w;
        rva2.x += e2 * m4.x; rva2.y += e2 * m4.y; rva2.z += e2 * m4.z; rva2.w += e2 * m4.w;
        rva3.x += e3 * m4.x; rva3.y += e3 * m4.y; rva3.z += e3 * m4.z; rva3.w += e3 * m4.w;
        if (s == 0) {
          f4 ev = {e0, e1, e2, e3};
          st_coh16(rwCur + ((size_t)b * 2048 + n) * 4, ev);  // for finalize/wps
          es0 += e0; es1 += e1; es2 += e2; es3 += e3;
        }
        float wps = sm.a.wps[nl];
        float onehot = (n == luB) ? 1.f : 0.f;
        float ww = sa * wps + (1.f - sa) * onehot;
        float keep = 1.f - onehot;
        float4 mn;
        mn.x = m4.x * keep + ww * wk.x;
        mn.y = m4.y * keep + ww * wk.y;
        mn.z = m4.z * keep + ww * wk.z;
        mn.w = m4.w * keep + ww * wk.w;
        *(float4*)&Mlds[nl * 64 + s * 4] = mn;  // LDS-resident M
      }
      es0 += __shfl_xor(es0, 16); es0 += __shfl_xor(es0, 32);
      es1 += __shfl_xor(es1, 16); es1 += __shfl_xor(es1, 32);
      es2 += __shfl_xor(es2, 16); es2 += __shfl_xor(es2, 32);
      es3 += __shfl_xor(es3, 16); es3 += __shfl_xor(es3, 32);
      if (lane == 0) {
        sm.a.wsum[wv * 4 + 0] = es0; sm.a.wsum[wv * 4 + 1] = es1;
        sm.a.wsum[wv * 4 + 2] = es2; sm.a.wsum[wv * 4 + 3] = es3;
      }
#define REDQ(v) { v += __shfl_xor(v, 16); v += __shfl_xor(v, 32); }
      REDQ(rva0.x) REDQ(rva0.y) REDQ(rva0.z) REDQ(rva0.w)
      REDQ(rva1.x) REDQ(rva1.y) REDQ(rva1.z) REDQ(rva1.w)
      REDQ(rva2.x) REDQ(rva2.y) REDQ(rva2.z) REDQ(rva2.w)
      REDQ(rva3.x) REDQ(rva3.y) REDQ(rva3.z) REDQ(rva3.w)
#undef REDQ
      if (q == 0) {
        atomicAdd(&sm.a.rvacc[0 * 64 + s * 4 + 0], rva0.x);
        atomicAdd(&sm.a.rvacc[0 * 64 + s * 4 + 1], rva0.y);
        atomicAdd(&sm.a.rvacc[0 * 64 + s * 4 + 2], rva0.z);
        atomicAdd(&sm.a.rvacc[0 * 64 + s * 4 + 3], rva0.w);
        atomicAdd(&sm.a.rvacc[1 * 64 + s * 4 + 0], rva1.x);
        atomicAdd(&sm.a.rvacc[1 * 64 + s * 4 + 1], rva1.y);
        atomicAdd(&sm.a.rvacc[1 * 64 + s * 4 + 2], rva1.z);
        atomicAdd(&sm.a.rvacc[1 * 64 + s * 4 + 3], rva1.w);
        atomicAdd(&sm.a.rvacc[2 * 64 + s * 4 + 0], rva2.x);
        atomicAdd(&sm.a.rvacc[2 * 64 + s * 4 + 1], rva2.y);
        atomicAdd(&sm.a.rvacc[2 * 64 + s * 4 + 2], rva2.z);
        atomicAdd(&sm.a.rvacc[2 * 64 + s * 4 + 3], rva2.w);
        atomicAdd(&sm.a.rvacc[3 * 64 + s * 4 + 0], rva3.x);
        atomicAdd(&sm.a.rvacc[3 * 64 + s * 4 + 1], rva3.y);
        atomicAdd(&sm.a.rvacc[3 * 64 + s * 4 + 2], rva3.z);
        atomicAdd(&sm.a.rvacc[3 * 64 + s * 4 + 3], rva3.w);
      }
      LBAR();
      if (tid < 4) {
        float ssum = 0.f;
        for (int w8 = 0; w8 < 8; ++w8) ssum += sm.a.wsum[w8 * 4 + tid];
        st_coh4(dp + (b * 4 + tid) * 4 + ch, ssum);  // denom partial
      }
      if (tid < 256) {
        float v = sm.a.rvacc[tid];
        atomicAdd(rvW + b * 256 + tid, v);  // device-scope, at MALL
      }
    }
    gsync(bar, ++rnd);
  }
}

extern "C" void kernel_launch(void* const* d_in, const int* in_sizes, int n_in,
                              void* d_out, int out_size, void* d_ws, size_t ws_size,
                              hipStream_t stream) {
  const float* x_seq = (const float*)d_in[0];
  const float* Wih = (const float*)d_in[1];
  const float* Whh = (const float*)d_in[2];
  const float* bih = (const float*)d_in[3];
  const float* bhh = (const float*)d_in[4];
  const float* Wout = (const float*)d_in[5];
  const float* bout = (const float*)d_in[6];
  const float* Wkey = (const float*)d_in[7];
  const float* bkey = (const float*)d_in[8];
  const float* alpha = (const float*)d_in[9];
  const float* gamma = (const float*)d_in[10];
  float* out = (float*)d_out;
  char* ws = (char*)d_ws;

  // zero the barrier flag region (ws is re-poisoned before every call)
  hipMemsetAsync(ws + 38673408, 0, 20480, stream);
  mann_mega<<<256, 512, 0, stream>>>(x_seq, Wih, Whh, bih, bhh, Wout, bout,
                                     Wkey, bkey, alpha, gamma, out, ws);
}